// Round 13
// baseline (51.316 us; speedup 1.0000x reference)
//
#include <hip/hip_runtime.h>
#include <hip/hip_fp16.h>
#include <stdint.h>

#define BB 8
#define NSQ 262144   // 512*512
#define TT 1024
#define FF 8
#define CH 9         // 8 weight features + 1 count channel
#define PP 128       // partials per batch
#define EPB 2048     // NSQ/PP elements per block
#define NONE_U32 0xFFFFFFFFu

using ull = unsigned long long;

// Order-preserving float->uint key packed with element index so min() matches
// stable argsort's first-occurrence-of-minimum.
__device__ inline ull pack_key(float v, unsigned idx) {
    unsigned u = __float_as_uint(v);
    unsigned key = (u & 0x80000000u) ? ~u : (u | 0x80000000u);
    return ((ull)key << 32) | (ull)idx;
}

__device__ inline unsigned pkrtz(float a, float b) {
    auto h = __builtin_amdgcn_cvt_pkrtz(a, b);   // v_cvt_pkrtz_f16_f32
    unsigned u; __builtin_memcpy(&u, &h, 4); return u;
}
__device__ inline float2 unpk(unsigned u) {
    __half2 h; __builtin_memcpy(&h, &u, 4);
    return __half22float2(h);
}

// First 5 binary-search levels as a register cndmask tree over the 31 static
// midpoint values (uniform per block). Identical compare sequence to the LDS
// loop (midpoints {(2k+1)<<(9-L)}), so semantics identical. (proven R5)
__device__ inline void tree5(float v, const float* __restrict__ cf,
                             int& lo_out, int& hi_out) {
    bool s0 = cf[0] <= v;
    float m1 = s0 ? cf[2] : cf[1];
    bool s1 = m1 <= v;
    float a2 = s1 ? cf[4] : cf[3];
    float b2 = s1 ? cf[6] : cf[5];
    float m2 = s0 ? b2 : a2;
    bool s2 = m2 <= v;
    float a3 = s2 ? cf[8]  : cf[7];
    float b3 = s2 ? cf[10] : cf[9];
    float c3 = s2 ? cf[12] : cf[11];
    float d3 = s2 ? cf[14] : cf[13];
    float e3 = s1 ? b3 : a3;
    float f3 = s1 ? d3 : c3;
    float m3 = s0 ? f3 : e3;
    bool s3 = m3 <= v;
    float a4 = s3 ? cf[16] : cf[15];
    float b4 = s3 ? cf[18] : cf[17];
    float c4 = s3 ? cf[20] : cf[19];
    float d4 = s3 ? cf[22] : cf[21];
    float e4 = s3 ? cf[24] : cf[23];
    float f4 = s3 ? cf[26] : cf[25];
    float g4 = s3 ? cf[28] : cf[27];
    float h4 = s3 ? cf[30] : cf[29];
    float i4 = s2 ? b4 : a4;
    float j4 = s2 ? d4 : c4;
    float k4 = s2 ? f4 : e4;
    float l4 = s2 ? h4 : g4;
    float n4 = s1 ? j4 : i4;
    float o4 = s1 ? l4 : k4;
    float m4 = s0 ? o4 : n4;
    bool s4 = m4 <= v;
    int lo = 0, hi = TT, m;
    m = (lo + hi) >> 1; lo = s0 ? m + 1 : lo; hi = s0 ? hi : m;
    m = (lo + hi) >> 1; lo = s1 ? m + 1 : lo; hi = s1 ? hi : m;
    m = (lo + hi) >> 1; lo = s2 ? m + 1 : lo; hi = s2 ? hi : m;
    m = (lo + hi) >> 1; lo = s3 ? m + 1 : lo; hi = s3 ? hi : m;
    m = (lo + hi) >> 1; lo = s4 ? m + 1 : lo; hi = s4 ? hi : m;
    lo_out = lo; hi_out = hi;
}

// 256 threads, 8 elems/thread (best-measured config, R10/R11). Phase C owns
// buckets t4..t4+3 CONTIGUOUS: metadata (tbase,c0..c3) stays in registers
// from the scan, sVal reads are sequential, partF stores are paired 8B.
__global__ __launch_bounds__(256, 4) void histo_kernel(
    const float* __restrict__ inp, const float* __restrict__ bins,
    const float* __restrict__ wts,
    __half* __restrict__ partF,        // [B][F][PP][TT] f16
    unsigned short* __restrict__ partC,// [B][PP][TT] u16
    ull* __restrict__ partMin)         // [PP][B]
{
    __shared__ uint4 sVal[EPB];        // 32 KB; head doubles as sbins + scratch
    __shared__ unsigned scnt[TT];      // 4 KB raw counts
    __shared__ unsigned sPfx[TT];      // 4 KB exclusive prefix
    float* sbins   = (float*)sVal;             // bytes [0, 4096) — dead before B
    ull* sMinW     = (ull*)(sVal + 256);       // bytes [4096, 4128)
    unsigned* sWs  = (unsigned*)(sVal + 258);  // bytes [4128, 4144)

    int b = blockIdx.x / PP, p = blockIdx.x % PP;
    int tid = threadIdx.x;
    int lane = tid & 63, wv = tid >> 6;

    const float4* inp4 = (const float4*)(inp + (size_t)b * NSQ + (size_t)p * EPB);
    const float4* wp   = (const float4*)(wts + ((size_t)b * NSQ + (size_t)p * EPB) * FF);

    for (int i = tid; i < TT; i += 256) { sbins[i] = bins[b * TT + i]; scnt[i] = 0u; }
    __syncthreads();

    // 31 coarse midpoints into registers (uniform broadcast reads)
    float cf[31];
    cf[0] = sbins[512]; cf[1] = sbins[256]; cf[2] = sbins[768];
    #pragma unroll
    for (int k = 0; k < 4; ++k)  cf[3 + k]  = sbins[128 + 256 * k];
    #pragma unroll
    for (int k = 0; k < 8; ++k)  cf[7 + k]  = sbins[64 + 128 * k];
    #pragma unroll
    for (int k = 0; k < 16; ++k) cf[15 + k] = sbins[32 + 64 * k];

    // ---- Phase A: search + count atomic (returns rank; id|rank in regs) ----
    unsigned idrank[8];
    ull lmin = ~0ull;
    #pragma unroll
    for (int it = 0; it < 2; ++it) {
        int q = it * 256 + tid;
        float4 v = inp4[q];

        int lo0, hi0, lo1, hi1, lo2, hi2, lo3, hi3;
        tree5(v.x, cf, lo0, hi0);
        tree5(v.y, cf, lo1, hi1);
        tree5(v.z, cf, lo2, hi2);
        tree5(v.w, cf, lo3, hi3);
        #pragma unroll
        for (int lev = 0; lev < 5; ++lev) {
            int m0 = (lo0 + hi0) >> 1, m1 = (lo1 + hi1) >> 1;
            int m2 = (lo2 + hi2) >> 1, m3 = (lo3 + hi3) >> 1;
            float b0 = sbins[m0], b1 = sbins[m1], b2 = sbins[m2], b3 = sbins[m3];
            if (b0 <= v.x) lo0 = m0 + 1; else hi0 = m0;
            if (b1 <= v.y) lo1 = m1 + 1; else hi1 = m1;
            if (b2 <= v.z) lo2 = m2 + 1; else hi2 = m2;
            if (b3 <= v.w) lo3 = m3 + 1; else hi3 = m3;
        }
        if (lo0 < hi0 && sbins[lo0] <= v.x) ++lo0;
        if (lo1 < hi1 && sbins[lo1] <= v.y) ++lo1;
        if (lo2 < hi2 && sbins[lo2] <= v.z) ++lo2;
        if (lo3 < hi3 && sbins[lo3] <= v.w) ++lo3;

        unsigned e0 = (unsigned)(p * EPB + q * 4);
        lmin = min(lmin, pack_key(v.x, e0 + 0));
        lmin = min(lmin, pack_key(v.y, e0 + 1));
        lmin = min(lmin, pack_key(v.z, e0 + 2));
        lmin = min(lmin, pack_key(v.w, e0 + 3));

        idrank[it*4+0] = (lo0 < TT) ? ((unsigned)lo0 << 16) | atomicAdd(&scnt[lo0], 1u) : NONE_U32;
        idrank[it*4+1] = (lo1 < TT) ? ((unsigned)lo1 << 16) | atomicAdd(&scnt[lo1], 1u) : NONE_U32;
        idrank[it*4+2] = (lo2 < TT) ? ((unsigned)lo2 << 16) | atomicAdd(&scnt[lo2], 1u) : NONE_U32;
        idrank[it*4+3] = (lo3 < TT) ? ((unsigned)lo3 << 16) | atomicAdd(&scnt[lo3], 1u) : NONE_U32;
    }

    // wave-level packed-min reduce (register-only; lane0 writes scratch)
    for (int off = 32; off > 0; off >>= 1) {
        unsigned hi32 = (unsigned)(lmin >> 32), lo32 = (unsigned)(lmin & 0xFFFFFFFFu);
        unsigned ohi = __shfl_down(hi32, off, 64);
        unsigned olo = __shfl_down(lo32, off, 64);
        ull other = ((ull)ohi << 32) | (ull)olo;
        if (other < lmin) lmin = other;
    }
    if (lane == 0) sMinW[wv] = lmin;
    __syncthreads();   // scnt + sMinW final (sbins now dead)

    if (tid == 0) {
        ull m = sMinW[0];
        #pragma unroll
        for (int w = 1; w < 4; ++w) { ull t = sMinW[w]; if (t < m) m = t; }
        partMin[(size_t)p * BB + b] = m;
    }

    // ---- counts -> global (u16) + exclusive prefix scan (4 buckets/thread) --
    int t4 = tid * 4;
    unsigned c0 = scnt[t4], c1 = scnt[t4 + 1], c2 = scnt[t4 + 2], c3 = scnt[t4 + 3];
    {
        ushort4 u4 = make_ushort4((unsigned short)c0, (unsigned short)c1,
                                  (unsigned short)c2, (unsigned short)c3);
        ushort4* dst = (ushort4*)(partC + ((size_t)b * PP + p) * TT);
        dst[tid] = u4;
    }
    unsigned l1 = c0 + c1, l2 = l1 + c2, l3 = l2 + c3;
    unsigned s = l3;
    #pragma unroll
    for (int off = 1; off < 64; off <<= 1) {
        unsigned n = __shfl_up(s, off, 64);
        if (lane >= off) s += n;
    }
    if (lane == 63) sWs[wv] = s;
    __syncthreads();
    unsigned wbase = 0;
    #pragma unroll
    for (int w = 0; w < 4; ++w) if (w < wv) wbase += sWs[w];
    unsigned tbase = wbase + s - l3;   // exclusive base of bucket t4
    sPfx[t4 + 0] = tbase;
    sPfx[t4 + 1] = tbase + c0;
    sPfx[t4 + 2] = tbase + l1;
    sPfx[t4 + 3] = tbase + l2;
    __syncthreads();

    // ---- Phase B: coalesced weights stream -> f16x8 scatter to sorted slot --
    #pragma unroll
    for (int k = 0; k < 8; ++k) {
        unsigned vr = idrank[k];
        size_t e = (size_t)((k >> 2) * 1024 + tid * 4 + (k & 3));
        float4 wa = wp[e * 2 + 0];
        float4 wb = wp[e * 2 + 1];
        if (vr != NONE_U32) {
            unsigned slot = sPfx[vr >> 16] + (vr & 0xFFFFu);
            sVal[slot] = make_uint4(pkrtz(wa.x, wa.y), pkrtz(wa.z, wa.w),
                                    pkrtz(wb.x, wb.y), pkrtz(wb.z, wb.w));
        }
    }
    __syncthreads();

    // ---- Phase C: buckets t4..t4+3 CONTIGUOUS in sVal; metadata (tbase,
    //      c0..c3) in registers -> zero LDS metadata reads, sequential reads --
    float acc[4][8];
    #pragma unroll
    for (int k = 0; k < 4; ++k)
        #pragma unroll
        for (int c = 0; c < 8; ++c) acc[k][c] = 0.f;

    unsigned e0 = tbase;
    unsigned e1 = e0 + c0, e2 = e1 + c1, e3 = e2 + c2, e4 = e3 + c3;
    #pragma unroll
    for (int k = 0; k < 4; ++k) {
        unsigned beg = (k == 0) ? e0 : (k == 1) ? e1 : (k == 2) ? e2 : e3;
        unsigned end = (k == 0) ? e1 : (k == 1) ? e2 : (k == 2) ? e3 : e4;
        for (unsigned e = beg; e < end; ++e) {
            uint4 u = sVal[e];
            float2 f0 = unpk(u.x), f1 = unpk(u.y), f2 = unpk(u.z), f3 = unpk(u.w);
            acc[k][0] += f0.x; acc[k][1] += f0.y; acc[k][2] += f1.x; acc[k][3] += f1.y;
            acc[k][4] += f2.x; acc[k][5] += f2.y; acc[k][6] += f3.x; acc[k][7] += f3.y;
        }
    }
    // paired f16 stores: per channel one uint2 (t4..t4+3) -> fully coalesced
    {
        size_t base = ((size_t)b * FF * PP + p) * TT;   // halves
        #pragma unroll
        for (int c = 0; c < 8; ++c) {
            uint2 v2 = make_uint2(pkrtz(acc[0][c], acc[1][c]),
                                  pkrtz(acc[2][c], acc[3][c]));
            *((uint2*)(partF + base + (size_t)c * PP * TT) + tid) = v2;
        }
    }
}

// High-occupancy P-reduction: one thread per (b,ch,t-pair), full device.
// red layout [B][CH][TT] f32.
__global__ __launch_bounds__(256) void reduce_kernel(
    const __half* __restrict__ partF, const unsigned short* __restrict__ partC,
    float* __restrict__ red)
{
    int idx = blockIdx.x * 256 + threadIdx.x;     // over B*CH*512
    if (idx >= BB * CH * 512) return;
    int bc = idx >> 9;           // (b,ch)
    int t2 = idx & 511;          // t-pair; t = 2*t2
    int b = bc / CH, ch = bc - b * CH;
    float s0 = 0.f, s1 = 0.f;
    if (ch < FF) {
        const unsigned* src = (const unsigned*)(partF + (((size_t)b * FF + ch) * PP) * TT) + t2;
        #pragma unroll 8
        for (int p = 0; p < PP; ++p) {
            float2 f = unpk(src[(size_t)p * 512]);
            s0 += f.x; s1 += f.y;
        }
    } else {
        const unsigned* src = (const unsigned*)(partC + ((size_t)b * PP) * TT) + t2;
        #pragma unroll 8
        for (int p = 0; p < PP; ++p) {
            unsigned u = src[(size_t)p * 512];
            s0 += (float)(u & 0xFFFFu);
            s1 += (float)(u >> 16);
        }
    }
    *((float2*)(red + (size_t)bc * TT) + t2) = make_float2(s0, s1);
}

// Light scan + output: one block per (b,f); shfl-based scans (3 barriers).
__global__ __launch_bounds__(256) void scan_kernel(
    const float* __restrict__ red, const ull* __restrict__ partMin,
    const float* __restrict__ wts, float* __restrict__ out)
{
    int b = blockIdx.x / FF, f = blockIdx.x % FF;
    int tid = threadIdx.x;
    int lane = tid & 63, wv = tid >> 6;
    __shared__ float sC[TT];      // inclusive counts
    __shared__ float sW[TT];      // inclusive feature cumsum
    __shared__ float sTot[2][4];
    __shared__ ull sMin2[2];
    __shared__ unsigned sMinIdx;

    // block min over partMin[p][b], p < PP=128 (threads 0..127 carry values)
    ull m = ~0ull;
    if (tid < PP) m = partMin[(size_t)tid * BB + b];
    for (int off = 32; off > 0; off >>= 1) {
        unsigned hi32 = (unsigned)(m >> 32), lo32 = (unsigned)(m & 0xFFFFFFFFu);
        unsigned ohi = __shfl_down(hi32, off, 64);
        unsigned olo = __shfl_down(lo32, off, 64);
        ull other = ((ull)ohi << 32) | (ull)olo;
        if (other < m) m = other;
    }
    if (lane == 0 && wv < 2) sMin2[wv] = m;

    // counts scan: serial-4 + wave shfl scan
    int t4 = tid * 4;
    float4 c4 = *(const float4*)(red + ((size_t)b * CH + FF) * TT + t4);
    float cl1 = c4.x + c4.y, cl2 = cl1 + c4.z, cl3 = cl2 + c4.w;
    float cs = cl3;
    #pragma unroll
    for (int off = 1; off < 64; off <<= 1) {
        float n = __shfl_up(cs, off, 64);
        if (lane >= off) cs += n;
    }
    if (lane == 63) sTot[0][wv] = cs;

    // feature scan
    float4 w4 = *(const float4*)(red + ((size_t)b * CH + f) * TT + t4);
    float wl1 = w4.x + w4.y, wl2 = wl1 + w4.z, wl3 = wl2 + w4.w;
    float ws = wl3;
    #pragma unroll
    for (int off = 1; off < 64; off <<= 1) {
        float n = __shfl_up(ws, off, 64);
        if (lane >= off) ws += n;
    }
    if (lane == 63) sTot[1][wv] = ws;
    __syncthreads();                       // barrier 1: sTot + sMin2 ready

    if (tid == 0) {
        ull mm = (sMin2[0] < sMin2[1]) ? sMin2[0] : sMin2[1];
        sMinIdx = (unsigned)(mm & 0xFFFFFFFFu);
    }
    float cbase = 0.f, wbase = 0.f;
    #pragma unroll
    for (int w = 0; w < 4; ++w) if (w < wv) { cbase += sTot[0][w]; wbase += sTot[1][w]; }
    float cexcl = cbase + cs - cl3;
    float wexcl = wbase + ws - wl3;
    sC[t4 + 0] = cexcl + c4.x;
    sC[t4 + 1] = cexcl + cl1;
    sC[t4 + 2] = cexcl + cl2;
    sC[t4 + 3] = cexcl + cl3;
    sW[t4 + 0] = wexcl + w4.x;
    sW[t4 + 1] = wexcl + wl1;
    sW[t4 + 2] = wexcl + wl2;
    sW[t4 + 3] = wexcl + wl3;
    __syncthreads();                       // barrier 2: sC/sW/sMinIdx ready

    float wmin = wts[((size_t)b * NSQ + sMinIdx) * FF + f];
    #pragma unroll
    for (int k = 0; k < 4; ++k) {
        int t = t4 + k;
        float scj = sC[t], Cj = sW[t];
        // reference quirk: counts==0 gathers cumsum_w[0] == weight of min element
        float csj = (scj == 0.f) ? wmin : Cj;
        float csjm1;
        if (t == 0) csjm1 = 0.f;
        else {
            float scp = sC[t - 1], Cp = sW[t - 1];
            csjm1 = (scp == 0.f) ? wmin : Cp;
        }
        out[((size_t)b * TT + t) * FF + f] = csj - csjm1;
    }
}

extern "C" void kernel_launch(void* const* d_in, const int* in_sizes, int n_in,
                              void* d_out, int out_size, void* d_ws, size_t ws_size,
                              hipStream_t stream)
{
    const float* inp  = (const float*)d_in[0];
    const float* bins = (const float*)d_in[1];
    const float* wts  = (const float*)d_in[2];
    float* out = (float*)d_out;

    char* w = (char*)d_ws;
    __half* partF = (__half*)w;          w += (size_t)BB * FF * PP * TT * 2;  // 16.8 MB
    unsigned short* partC = (unsigned short*)w; w += (size_t)BB * PP * TT * 2; // 2.1 MB
    ull* partMin = (ull*)w;              w += (size_t)PP * BB * 8;
    float* red = (float*)w;              // B*CH*TT*4 = 294912 B

    histo_kernel<<<dim3(BB * PP), dim3(256), 0, stream>>>(
        inp, bins, wts, partF, partC, partMin);
    reduce_kernel<<<dim3((BB * CH * 512 + 255) / 256), dim3(256), 0, stream>>>(
        partF, partC, red);
    scan_kernel<<<dim3(BB * FF), dim3(256), 0, stream>>>(
        red, partMin, wts, out);
}

// Round 14
// 43.654 us; speedup vs baseline: 1.1755x; 1.1755x over previous
//
#include <hip/hip_runtime.h>
#include <hip/hip_fp16.h>
#include <stdint.h>

#define BB 8
#define NSQ 262144   // 512*512
#define TT 1024
#define FF 8
#define CH 9         // 8 weight features + 1 count channel
#define PP 128       // partials per batch
#define EPB 2048     // NSQ/PP elements per block
#define NONE_U32 0xFFFFFFFFu

using ull = unsigned long long;

// Order-preserving float->uint key packed with element index so min() matches
// stable argsort's first-occurrence-of-minimum.
__device__ inline ull pack_key(float v, unsigned idx) {
    unsigned u = __float_as_uint(v);
    unsigned key = (u & 0x80000000u) ? ~u : (u | 0x80000000u);
    return ((ull)key << 32) | (ull)idx;
}

__device__ inline unsigned pkrtz(float a, float b) {
    auto h = __builtin_amdgcn_cvt_pkrtz(a, b);   // v_cvt_pkrtz_f16_f32
    unsigned u; __builtin_memcpy(&u, &h, 4); return u;
}
__device__ inline float2 unpk(unsigned u) {
    __half2 h; __builtin_memcpy(&h, &u, 4);
    return __half22float2(h);
}

// First 5 binary-search levels as a register cndmask tree over the 31 static
// midpoint values (uniform per block). Identical compare sequence to the LDS
// loop (midpoints {(2k+1)<<(9-L)}), so semantics identical. (proven R5)
__device__ inline void tree5(float v, const float* __restrict__ cf,
                             int& lo_out, int& hi_out) {
    bool s0 = cf[0] <= v;
    float m1 = s0 ? cf[2] : cf[1];
    bool s1 = m1 <= v;
    float a2 = s1 ? cf[4] : cf[3];
    float b2 = s1 ? cf[6] : cf[5];
    float m2 = s0 ? b2 : a2;
    bool s2 = m2 <= v;
    float a3 = s2 ? cf[8]  : cf[7];
    float b3 = s2 ? cf[10] : cf[9];
    float c3 = s2 ? cf[12] : cf[11];
    float d3 = s2 ? cf[14] : cf[13];
    float e3 = s1 ? b3 : a3;
    float f3 = s1 ? d3 : c3;
    float m3 = s0 ? f3 : e3;
    bool s3 = m3 <= v;
    float a4 = s3 ? cf[16] : cf[15];
    float b4 = s3 ? cf[18] : cf[17];
    float c4 = s3 ? cf[20] : cf[19];
    float d4 = s3 ? cf[22] : cf[21];
    float e4 = s3 ? cf[24] : cf[23];
    float f4 = s3 ? cf[26] : cf[25];
    float g4 = s3 ? cf[28] : cf[27];
    float h4 = s3 ? cf[30] : cf[29];
    float i4 = s2 ? b4 : a4;
    float j4 = s2 ? d4 : c4;
    float k4 = s2 ? f4 : e4;
    float l4 = s2 ? h4 : g4;
    float n4 = s1 ? j4 : i4;
    float o4 = s1 ? l4 : k4;
    float m4 = s0 ? o4 : n4;
    bool s4 = m4 <= v;
    int lo = 0, hi = TT, m;
    m = (lo + hi) >> 1; lo = s0 ? m + 1 : lo; hi = s0 ? hi : m;
    m = (lo + hi) >> 1; lo = s1 ? m + 1 : lo; hi = s1 ? hi : m;
    m = (lo + hi) >> 1; lo = s2 ? m + 1 : lo; hi = s2 ? hi : m;
    m = (lo + hi) >> 1; lo = s3 ? m + 1 : lo; hi = s3 ? hi : m;
    m = (lo + hi) >> 1; lo = s4 ? m + 1 : lo; hi = s4 ? hi : m;
    lo_out = lo; hi_out = hi;
}

// Fused: search + count(+rank) + scatter VALUES (f16x8) to sorted LDS slots +
// owner register summation. Weights are PREFETCHED: iter0 at kernel top
// (lands under sbins staging + searches), iter1 issued before the scan
// barriers. Best-measured configuration (R11, 43.78us total).
__global__ __launch_bounds__(256, 4) void histo_kernel(
    const float* __restrict__ inp, const float* __restrict__ bins,
    const float* __restrict__ wts,
    __half* __restrict__ partF,        // [B][F][PP][TT] f16
    unsigned short* __restrict__ partC,// [B][PP][TT] u16
    ull* __restrict__ partMin)         // [PP][B]
{
    __shared__ uint4 sVal[EPB];        // 32 KB; head doubles as sbins + scratch
    __shared__ unsigned scnt[TT];      // 4 KB raw counts
    __shared__ unsigned sPfx[TT];      // 4 KB exclusive prefix
    float* sbins   = (float*)sVal;             // bytes [0, 4096) — dead before B
    ull* sMinW     = (ull*)(sVal + 256);       // bytes [4096, 4128)
    unsigned* sWs  = (unsigned*)(sVal + 258);  // bytes [4128, 4144)

    int b = blockIdx.x / PP, p = blockIdx.x % PP;
    int tid = threadIdx.x;
    int lane = tid & 63, wv = tid >> 6;

    const float4* inp4 = (const float4*)(inp + (size_t)b * NSQ + (size_t)p * EPB);
    const float4* wp   = (const float4*)(wts + ((size_t)b * NSQ + (size_t)p * EPB) * FF);

    // ---- issue input + iter0 weight loads FIRST (hide under staging+search)
    float4 v0 = inp4[tid];
    float4 v1 = inp4[256 + tid];
    size_t w0b = (size_t)tid * 8;
    float4 p0 = wp[w0b+0], p1 = wp[w0b+1], p2 = wp[w0b+2], p3 = wp[w0b+3];
    float4 p4 = wp[w0b+4], p5 = wp[w0b+5], p6 = wp[w0b+6], p7 = wp[w0b+7];

    for (int i = tid; i < TT; i += 256) { sbins[i] = bins[b * TT + i]; scnt[i] = 0u; }
    __syncthreads();

    // 31 coarse midpoints into registers (uniform broadcast reads)
    float cf[31];
    cf[0] = sbins[512]; cf[1] = sbins[256]; cf[2] = sbins[768];
    #pragma unroll
    for (int k = 0; k < 4; ++k)  cf[3 + k]  = sbins[128 + 256 * k];
    #pragma unroll
    for (int k = 0; k < 8; ++k)  cf[7 + k]  = sbins[64 + 128 * k];
    #pragma unroll
    for (int k = 0; k < 16; ++k) cf[15 + k] = sbins[32 + 64 * k];

    // ---- Phase A: searches (4-way ILP per iter) + count atomics ----
    unsigned idrank[8];
    ull lmin = ~0ull;
    {
        float4 v = v0;
        int lo0, hi0, lo1, hi1, lo2, hi2, lo3, hi3;
        tree5(v.x, cf, lo0, hi0);
        tree5(v.y, cf, lo1, hi1);
        tree5(v.z, cf, lo2, hi2);
        tree5(v.w, cf, lo3, hi3);
        #pragma unroll
        for (int lev = 0; lev < 5; ++lev) {
            int m0 = (lo0 + hi0) >> 1, m1 = (lo1 + hi1) >> 1;
            int m2 = (lo2 + hi2) >> 1, m3 = (lo3 + hi3) >> 1;
            float b0 = sbins[m0], b1 = sbins[m1], b2 = sbins[m2], b3 = sbins[m3];
            if (b0 <= v.x) lo0 = m0 + 1; else hi0 = m0;
            if (b1 <= v.y) lo1 = m1 + 1; else hi1 = m1;
            if (b2 <= v.z) lo2 = m2 + 1; else hi2 = m2;
            if (b3 <= v.w) lo3 = m3 + 1; else hi3 = m3;
        }
        if (lo0 < hi0 && sbins[lo0] <= v.x) ++lo0;
        if (lo1 < hi1 && sbins[lo1] <= v.y) ++lo1;
        if (lo2 < hi2 && sbins[lo2] <= v.z) ++lo2;
        if (lo3 < hi3 && sbins[lo3] <= v.w) ++lo3;
        unsigned e0 = (unsigned)(p * EPB + tid * 4);
        lmin = min(lmin, pack_key(v.x, e0 + 0));
        lmin = min(lmin, pack_key(v.y, e0 + 1));
        lmin = min(lmin, pack_key(v.z, e0 + 2));
        lmin = min(lmin, pack_key(v.w, e0 + 3));
        idrank[0] = (lo0 < TT) ? ((unsigned)lo0 << 16) | atomicAdd(&scnt[lo0], 1u) : NONE_U32;
        idrank[1] = (lo1 < TT) ? ((unsigned)lo1 << 16) | atomicAdd(&scnt[lo1], 1u) : NONE_U32;
        idrank[2] = (lo2 < TT) ? ((unsigned)lo2 << 16) | atomicAdd(&scnt[lo2], 1u) : NONE_U32;
        idrank[3] = (lo3 < TT) ? ((unsigned)lo3 << 16) | atomicAdd(&scnt[lo3], 1u) : NONE_U32;
    }
    {
        float4 v = v1;
        int lo0, hi0, lo1, hi1, lo2, hi2, lo3, hi3;
        tree5(v.x, cf, lo0, hi0);
        tree5(v.y, cf, lo1, hi1);
        tree5(v.z, cf, lo2, hi2);
        tree5(v.w, cf, lo3, hi3);
        #pragma unroll
        for (int lev = 0; lev < 5; ++lev) {
            int m0 = (lo0 + hi0) >> 1, m1 = (lo1 + hi1) >> 1;
            int m2 = (lo2 + hi2) >> 1, m3 = (lo3 + hi3) >> 1;
            float b0 = sbins[m0], b1 = sbins[m1], b2 = sbins[m2], b3 = sbins[m3];
            if (b0 <= v.x) lo0 = m0 + 1; else hi0 = m0;
            if (b1 <= v.y) lo1 = m1 + 1; else hi1 = m1;
            if (b2 <= v.z) lo2 = m2 + 1; else hi2 = m2;
            if (b3 <= v.w) lo3 = m3 + 1; else hi3 = m3;
        }
        if (lo0 < hi0 && sbins[lo0] <= v.x) ++lo0;
        if (lo1 < hi1 && sbins[lo1] <= v.y) ++lo1;
        if (lo2 < hi2 && sbins[lo2] <= v.z) ++lo2;
        if (lo3 < hi3 && sbins[lo3] <= v.w) ++lo3;
        unsigned e0 = (unsigned)(p * EPB + 1024 + tid * 4);
        lmin = min(lmin, pack_key(v.x, e0 + 0));
        lmin = min(lmin, pack_key(v.y, e0 + 1));
        lmin = min(lmin, pack_key(v.z, e0 + 2));
        lmin = min(lmin, pack_key(v.w, e0 + 3));
        idrank[4] = (lo0 < TT) ? ((unsigned)lo0 << 16) | atomicAdd(&scnt[lo0], 1u) : NONE_U32;
        idrank[5] = (lo1 < TT) ? ((unsigned)lo1 << 16) | atomicAdd(&scnt[lo1], 1u) : NONE_U32;
        idrank[6] = (lo2 < TT) ? ((unsigned)lo2 << 16) | atomicAdd(&scnt[lo2], 1u) : NONE_U32;
        idrank[7] = (lo3 < TT) ? ((unsigned)lo3 << 16) | atomicAdd(&scnt[lo3], 1u) : NONE_U32;
    }

    // ---- convert iter0 weights to f16x8 (loads landed under searches) ----
    uint4 u0 = make_uint4(pkrtz(p0.x,p0.y), pkrtz(p0.z,p0.w), pkrtz(p1.x,p1.y), pkrtz(p1.z,p1.w));
    uint4 u1 = make_uint4(pkrtz(p2.x,p2.y), pkrtz(p2.z,p2.w), pkrtz(p3.x,p3.y), pkrtz(p3.z,p3.w));
    uint4 u2 = make_uint4(pkrtz(p4.x,p4.y), pkrtz(p4.z,p4.w), pkrtz(p5.x,p5.y), pkrtz(p5.z,p5.w));
    uint4 u3 = make_uint4(pkrtz(p6.x,p6.y), pkrtz(p6.z,p6.w), pkrtz(p7.x,p7.y), pkrtz(p7.z,p7.w));

    // ---- issue iter1 weight loads now; scan barriers drain them ----
    size_t w1b = (size_t)(256 + tid) * 8;
    float4 q0 = wp[w1b+0], q1 = wp[w1b+1], q2 = wp[w1b+2], q3 = wp[w1b+3];
    float4 q4 = wp[w1b+4], q5 = wp[w1b+5], q6 = wp[w1b+6], q7 = wp[w1b+7];

    // wave-level packed-min reduce (register-only; lane0 writes scratch)
    for (int off = 32; off > 0; off >>= 1) {
        unsigned hi32 = (unsigned)(lmin >> 32), lo32 = (unsigned)(lmin & 0xFFFFFFFFu);
        unsigned ohi = __shfl_down(hi32, off, 64);
        unsigned olo = __shfl_down(lo32, off, 64);
        ull other = ((ull)ohi << 32) | (ull)olo;
        if (other < lmin) lmin = other;
    }
    if (lane == 0) sMinW[wv] = lmin;
    __syncthreads();   // scnt + sMinW final (sbins now dead)

    if (tid == 0) {
        ull m = sMinW[0];
        #pragma unroll
        for (int w = 1; w < 4; ++w) { ull t = sMinW[w]; if (t < m) m = t; }
        partMin[(size_t)p * BB + b] = m;
    }

    // ---- counts -> global (u16) + exclusive prefix scan (4 buckets/thread) --
    int t4 = tid * 4;
    unsigned c0 = scnt[t4], c1 = scnt[t4 + 1], c2 = scnt[t4 + 2], c3 = scnt[t4 + 3];
    {
        ushort4 u4 = make_ushort4((unsigned short)c0, (unsigned short)c1,
                                  (unsigned short)c2, (unsigned short)c3);
        ushort4* dst = (ushort4*)(partC + ((size_t)b * PP + p) * TT);
        dst[tid] = u4;
    }
    unsigned l1 = c0 + c1, l2 = l1 + c2, l3 = l2 + c3;
    unsigned s = l3;
    #pragma unroll
    for (int off = 1; off < 64; off <<= 1) {
        unsigned n = __shfl_up(s, off, 64);
        if (lane >= off) s += n;
    }
    if (lane == 63) sWs[wv] = s;
    __syncthreads();
    unsigned wbase = 0;
    #pragma unroll
    for (int w = 0; w < 4; ++w) if (w < wv) wbase += sWs[w];
    unsigned tbase = wbase + s - l3;   // exclusive base of bucket t4
    sPfx[t4 + 0] = tbase;
    sPfx[t4 + 1] = tbase + c0;
    sPfx[t4 + 2] = tbase + l1;
    sPfx[t4 + 3] = tbase + l2;
    __syncthreads();

    // ---- Phase B: scatter f16x8 rows to sorted slots (all from registers) --
    if (idrank[0] != NONE_U32) sVal[sPfx[idrank[0] >> 16] + (idrank[0] & 0xFFFFu)] = u0;
    if (idrank[1] != NONE_U32) sVal[sPfx[idrank[1] >> 16] + (idrank[1] & 0xFFFFu)] = u1;
    if (idrank[2] != NONE_U32) sVal[sPfx[idrank[2] >> 16] + (idrank[2] & 0xFFFFu)] = u2;
    if (idrank[3] != NONE_U32) sVal[sPfx[idrank[3] >> 16] + (idrank[3] & 0xFFFFu)] = u3;
    {
        uint4 w0 = make_uint4(pkrtz(q0.x,q0.y), pkrtz(q0.z,q0.w), pkrtz(q1.x,q1.y), pkrtz(q1.z,q1.w));
        uint4 w1 = make_uint4(pkrtz(q2.x,q2.y), pkrtz(q2.z,q2.w), pkrtz(q3.x,q3.y), pkrtz(q3.z,q3.w));
        uint4 w2 = make_uint4(pkrtz(q4.x,q4.y), pkrtz(q4.z,q4.w), pkrtz(q5.x,q5.y), pkrtz(q5.z,q5.w));
        uint4 w3 = make_uint4(pkrtz(q6.x,q6.y), pkrtz(q6.z,q6.w), pkrtz(q7.x,q7.y), pkrtz(q7.z,q7.w));
        if (idrank[4] != NONE_U32) sVal[sPfx[idrank[4] >> 16] + (idrank[4] & 0xFFFFu)] = w0;
        if (idrank[5] != NONE_U32) sVal[sPfx[idrank[5] >> 16] + (idrank[5] & 0xFFFFu)] = w1;
        if (idrank[6] != NONE_U32) sVal[sPfx[idrank[6] >> 16] + (idrank[6] & 0xFFFFu)] = w2;
        if (idrank[7] != NONE_U32) sVal[sPfx[idrank[7] >> 16] + (idrank[7] & 0xFFFFu)] = w3;
    }
    __syncthreads();

    // ---- Phase C: bucket-owner summation over LINEAR LDS -> f16 partials ----
    #pragma unroll
    for (int k = 0; k < 4; ++k) {
        int t = tid + 256 * k;
        unsigned start = sPfx[t];
        unsigned end = start + scnt[t];
        float a0 = 0.f, a1 = 0.f, a2 = 0.f, a3 = 0.f;
        float a4 = 0.f, a5 = 0.f, a6 = 0.f, a7 = 0.f;
        for (unsigned e = start; e < end; ++e) {
            uint4 v = sVal[e];
            float2 f0 = unpk(v.x), f1 = unpk(v.y);
            float2 f2 = unpk(v.z), f3 = unpk(v.w);
            a0 += f0.x; a1 += f0.y; a2 += f1.x; a3 += f1.y;
            a4 += f2.x; a5 += f2.y; a6 += f3.x; a7 += f3.y;
        }
        size_t pb = ((size_t)b * FF * PP + p) * TT + t;
        partF[pb + 0 * (size_t)PP * TT] = __float2half(a0);
        partF[pb + 1 * (size_t)PP * TT] = __float2half(a1);
        partF[pb + 2 * (size_t)PP * TT] = __float2half(a2);
        partF[pb + 3 * (size_t)PP * TT] = __float2half(a3);
        partF[pb + 4 * (size_t)PP * TT] = __float2half(a4);
        partF[pb + 5 * (size_t)PP * TT] = __float2half(a5);
        partF[pb + 6 * (size_t)PP * TT] = __float2half(a6);
        partF[pb + 7 * (size_t)PP * TT] = __float2half(a7);
    }
}

// High-occupancy P-reduction: one thread per (b,ch,t-pair), full device.
// red layout [B][CH][TT] f32.
__global__ __launch_bounds__(256) void reduce_kernel(
    const __half* __restrict__ partF, const unsigned short* __restrict__ partC,
    float* __restrict__ red)
{
    int idx = blockIdx.x * 256 + threadIdx.x;     // over B*CH*512
    if (idx >= BB * CH * 512) return;
    int bc = idx >> 9;           // (b,ch)
    int t2 = idx & 511;          // t-pair; t = 2*t2
    int b = bc / CH, ch = bc - b * CH;
    float s0 = 0.f, s1 = 0.f;
    if (ch < FF) {
        const unsigned* src = (const unsigned*)(partF + (((size_t)b * FF + ch) * PP) * TT) + t2;
        #pragma unroll 8
        for (int p = 0; p < PP; ++p) {
            float2 f = unpk(src[(size_t)p * 512]);
            s0 += f.x; s1 += f.y;
        }
    } else {
        const unsigned* src = (const unsigned*)(partC + ((size_t)b * PP) * TT) + t2;
        #pragma unroll 8
        for (int p = 0; p < PP; ++p) {
            unsigned u = src[(size_t)p * 512];
            s0 += (float)(u & 0xFFFFu);
            s1 += (float)(u >> 16);
        }
    }
    *((float2*)(red + (size_t)bc * TT) + t2) = make_float2(s0, s1);
}

// Light scan + output: one block per (b,f); shfl-based scans (3 barriers).
__global__ __launch_bounds__(256) void scan_kernel(
    const float* __restrict__ red, const ull* __restrict__ partMin,
    const float* __restrict__ wts, float* __restrict__ out)
{
    int b = blockIdx.x / FF, f = blockIdx.x % FF;
    int tid = threadIdx.x;
    int lane = tid & 63, wv = tid >> 6;
    __shared__ float sC[TT];      // inclusive counts
    __shared__ float sW[TT];      // inclusive feature cumsum
    __shared__ float sTot[2][4];
    __shared__ ull sMin2[2];
    __shared__ unsigned sMinIdx;

    // block min over partMin[p][b], p < PP=128 (threads 0..127 carry values)
    ull m = ~0ull;
    if (tid < PP) m = partMin[(size_t)tid * BB + b];
    for (int off = 32; off > 0; off >>= 1) {
        unsigned hi32 = (unsigned)(m >> 32), lo32 = (unsigned)(m & 0xFFFFFFFFu);
        unsigned ohi = __shfl_down(hi32, off, 64);
        unsigned olo = __shfl_down(lo32, off, 64);
        ull other = ((ull)ohi << 32) | (ull)olo;
        if (other < m) m = other;
    }
    if (lane == 0 && wv < 2) sMin2[wv] = m;

    // counts scan: serial-4 + wave shfl scan
    int t4 = tid * 4;
    float4 c4 = *(const float4*)(red + ((size_t)b * CH + FF) * TT + t4);
    float cl1 = c4.x + c4.y, cl2 = cl1 + c4.z, cl3 = cl2 + c4.w;
    float cs = cl3;
    #pragma unroll
    for (int off = 1; off < 64; off <<= 1) {
        float n = __shfl_up(cs, off, 64);
        if (lane >= off) cs += n;
    }
    if (lane == 63) sTot[0][wv] = cs;

    // feature scan
    float4 w4 = *(const float4*)(red + ((size_t)b * CH + f) * TT + t4);
    float wl1 = w4.x + w4.y, wl2 = wl1 + w4.z, wl3 = wl2 + w4.w;
    float ws = wl3;
    #pragma unroll
    for (int off = 1; off < 64; off <<= 1) {
        float n = __shfl_up(ws, off, 64);
        if (lane >= off) ws += n;
    }
    if (lane == 63) sTot[1][wv] = ws;
    __syncthreads();                       // barrier 1: sTot + sMin2 ready

    if (tid == 0) {
        ull mm = (sMin2[0] < sMin2[1]) ? sMin2[0] : sMin2[1];
        sMinIdx = (unsigned)(mm & 0xFFFFFFFFu);
    }
    float cbase = 0.f, wbase = 0.f;
    #pragma unroll
    for (int w = 0; w < 4; ++w) if (w < wv) { cbase += sTot[0][w]; wbase += sTot[1][w]; }
    float cexcl = cbase + cs - cl3;
    float wexcl = wbase + ws - wl3;
    sC[t4 + 0] = cexcl + c4.x;
    sC[t4 + 1] = cexcl + cl1;
    sC[t4 + 2] = cexcl + cl2;
    sC[t4 + 3] = cexcl + cl3;
    sW[t4 + 0] = wexcl + w4.x;
    sW[t4 + 1] = wexcl + wl1;
    sW[t4 + 2] = wexcl + wl2;
    sW[t4 + 3] = wexcl + wl3;
    __syncthreads();                       // barrier 2: sC/sW/sMinIdx ready

    float wmin = wts[((size_t)b * NSQ + sMinIdx) * FF + f];
    #pragma unroll
    for (int k = 0; k < 4; ++k) {
        int t = t4 + k;
        float scj = sC[t], Cj = sW[t];
        // reference quirk: counts==0 gathers cumsum_w[0] == weight of min element
        float csj = (scj == 0.f) ? wmin : Cj;
        float csjm1;
        if (t == 0) csjm1 = 0.f;
        else {
            float scp = sC[t - 1], Cp = sW[t - 1];
            csjm1 = (scp == 0.f) ? wmin : Cp;
        }
        out[((size_t)b * TT + t) * FF + f] = csj - csjm1;
    }
}

extern "C" void kernel_launch(void* const* d_in, const int* in_sizes, int n_in,
                              void* d_out, int out_size, void* d_ws, size_t ws_size,
                              hipStream_t stream)
{
    const float* inp  = (const float*)d_in[0];
    const float* bins = (const float*)d_in[1];
    const float* wts  = (const float*)d_in[2];
    float* out = (float*)d_out;

    char* w = (char*)d_ws;
    __half* partF = (__half*)w;          w += (size_t)BB * FF * PP * TT * 2;  // 16.8 MB
    unsigned short* partC = (unsigned short*)w; w += (size_t)BB * PP * TT * 2; // 2.1 MB
    ull* partMin = (ull*)w;              w += (size_t)PP * BB * 8;
    float* red = (float*)w;              // B*CH*TT*4 = 294912 B

    histo_kernel<<<dim3(BB * PP), dim3(256), 0, stream>>>(
        inp, bins, wts, partF, partC, partMin);
    reduce_kernel<<<dim3((BB * CH * 512 + 255) / 256), dim3(256), 0, stream>>>(
        partF, partC, red);
    scan_kernel<<<dim3(BB * FF), dim3(256), 0, stream>>>(
        red, partMin, wts, out);
}